// Round 3
// baseline (75.804 us; speedup 1.0000x reference)
//
#include <hip/hip_runtime.h>
#include <hip/hip_bf16.h>

// LinearMinimumBit: y = x @ dequant3bit(W)^T + bias
// x:[64,8192] f32, weight_q3:[4194304,6] int32 (byte values), weight_norm:[4194304] f32,
// bias:[8192] f32 -> out:[64,8192] f32
//
// Barrier-free design: each lane dequantizes exactly the 8 weights its MFMA
// B-fragment needs (8 consecutive k of one col = 3 packed int32s = 12B).
// No LDS, no __syncthreads, depth-4 register prefetch.
//
// ws: [0,1MB) x as bf16; [1MB, 1MB+KS*2MB) partials [KS][64][8192] f32

#define BATCH   64
#define IN_F    8192
#define OUT_F   8192

typedef __attribute__((ext_vector_type(8))) short bf16x8;
typedef __attribute__((ext_vector_type(4))) float f32x4;

__device__ __forceinline__ ushort f2bf(float f) {
  union { float f; unsigned u; } a; a.f = f;
  unsigned r = a.u + 0x7fffu + ((a.u >> 16) & 1u);
  return (ushort)(r >> 16);
}

__global__ void __launch_bounds__(256) xcvt_kernel(const float* __restrict__ x,
                                                   ushort* __restrict__ xb) {
  int i = blockIdx.x * 256 + threadIdx.x;
  float4 v = ((const float4*)x)[i];
  ushort4 o;
  o.x = f2bf(v.x); o.y = f2bf(v.y); o.z = f2bf(v.z); o.w = f2bf(v.w);
  ((ushort4*)xb)[i] = o;
}

// 3 byte-values + norm -> 8 bf16 weights (w = v*(2n/7) - n), fragment-ordered
__device__ __forceinline__ bf16x8 dqfrag(int b0, int b1, int b2, float nrm) {
  float c1 = nrm * (2.0f / 7.0f);
  float c0 = nrm;
  int v0 = (b0 >> 5) & 7;
  int v1 = (b0 >> 2) & 7;
  int v2 = ((b0 & 3) << 1) | ((b1 >> 7) & 1);
  int v3 = (b1 >> 4) & 7;
  int v4 = (b1 >> 1) & 7;
  int v5 = ((b1 & 1) << 2) | ((b2 >> 6) & 3);
  int v6 = (b2 >> 3) & 7;
  int v7 = b2 & 7;
  union { __hip_bfloat162 h[4]; bf16x8 v; } r;
  r.h[0] = __float22bfloat162_rn(make_float2(fmaf((float)v0, c1, -c0), fmaf((float)v1, c1, -c0)));
  r.h[1] = __float22bfloat162_rn(make_float2(fmaf((float)v2, c1, -c0), fmaf((float)v3, c1, -c0)));
  r.h[2] = __float22bfloat162_rn(make_float2(fmaf((float)v4, c1, -c0), fmaf((float)v5, c1, -c0)));
  r.h[3] = __float22bfloat162_rn(make_float2(fmaf((float)v6, c1, -c0), fmaf((float)v7, c1, -c0)));
  return r.v;
}

template <int KS>
__global__ void __launch_bounds__(256) gemm3b_kernel(const ushort* __restrict__ xb,
                                                     const int* __restrict__ wq,
                                                     const float* __restrict__ wnorm,
                                                     float* __restrict__ partial) {
  constexpr int K_SLICE = IN_F / KS;
  constexpr int NIT = K_SLICE / 32;   // 32-k step per iteration

  const int tid  = threadIdx.x;
  const int lane = tid & 63;
  const int w    = tid >> 6;          // 4 waves; wave w owns cols [nb, nb+32)
  const int l15  = lane & 15;
  const int h    = lane >> 4;         // k-chunk 0..3 within 32-k step
  const int nb   = blockIdx.x * 128 + w * 32;
  const int s    = blockIdx.y;
  const int kbase = s * K_SLICE;

  // frag0: col = nb + l15; frag1: col = nb + 16 + l15
  // lane's group along k for iter it: g = row*512 + kbase/16 + it*2 + (h>>1), half = h&1
  const long row0 = nb + l15;
  const int* __restrict__ pq0 = wq + (row0 * 512 + (long)(kbase >> 4) + (h >> 1)) * 6 + (h & 1) * 3;
  const int* __restrict__ pq1 = pq0 + (long)16 * 512 * 6;
  const float* __restrict__ pn0 = wnorm + row0 * 512 + (kbase >> 4) + (h >> 1);
  const float* __restrict__ pn1 = pn0 + 16 * 512;
  const ushort* __restrict__ pa = xb + l15 * IN_F + kbase + h * 8;

  f32x4 acc[2][4];
  #pragma unroll
  for (int n = 0; n < 2; ++n)
    #pragma unroll
    for (int m = 0; m < 4; ++m) acc[n][m] = (f32x4){0.f, 0.f, 0.f, 0.f};

  // depth-4 prefetch slots (named scalars only; offsets compile-time -> imm-folded)
  int q0a0, q1a0, q2a0, q0b0, q1b0, q2b0; float na0, nb0;
  int q0a1, q1a1, q2a1, q0b1, q1b1, q2b1; float na1, nb1;
  int q0a2, q1a2, q2a2, q0b2, q1b2, q2b2; float na2, nb2;
  int q0a3, q1a3, q2a3, q0b3, q1b3, q2b3; float na3, nb3;

#define LOADS(SL, IT)                                   \
  do {                                                  \
    q0a##SL = pq0[(IT) * 12 + 0];                       \
    q1a##SL = pq0[(IT) * 12 + 1];                       \
    q2a##SL = pq0[(IT) * 12 + 2];                       \
    na##SL  = pn0[(IT) * 2];                            \
    q0b##SL = pq1[(IT) * 12 + 0];                       \
    q1b##SL = pq1[(IT) * 12 + 1];                       \
    q2b##SL = pq1[(IT) * 12 + 2];                       \
    nb##SL  = pn1[(IT) * 2];                            \
  } while (0)

#define DQMMA(SL, IT)                                                                  \
  do {                                                                                 \
    bf16x8 bf0 = dqfrag(q0a##SL, q1a##SL, q2a##SL, na##SL);                            \
    bf16x8 bf1 = dqfrag(q0b##SL, q1b##SL, q2b##SL, nb##SL);                            \
    const ushort* pA = pa + (IT) * 32;                                                 \
    bf16x8 a0 = *(const bf16x8*)(pA);                                                  \
    bf16x8 a1 = *(const bf16x8*)(pA + 16 * IN_F);                                      \
    bf16x8 a2 = *(const bf16x8*)(pA + 32 * IN_F);                                      \
    bf16x8 a3 = *(const bf16x8*)(pA + 48 * IN_F);                                      \
    acc[0][0] = __builtin_amdgcn_mfma_f32_16x16x32_bf16(a0, bf0, acc[0][0], 0, 0, 0);  \
    acc[1][0] = __builtin_amdgcn_mfma_f32_16x16x32_bf16(a0, bf1, acc[1][0], 0, 0, 0);  \
    acc[0][1] = __builtin_amdgcn_mfma_f32_16x16x32_bf16(a1, bf0, acc[0][1], 0, 0, 0);  \
    acc[1][1] = __builtin_amdgcn_mfma_f32_16x16x32_bf16(a1, bf1, acc[1][1], 0, 0, 0);  \
    acc[0][2] = __builtin_amdgcn_mfma_f32_16x16x32_bf16(a2, bf0, acc[0][2], 0, 0, 0);  \
    acc[1][2] = __builtin_amdgcn_mfma_f32_16x16x32_bf16(a2, bf1, acc[1][2], 0, 0, 0);  \
    acc[0][3] = __builtin_amdgcn_mfma_f32_16x16x32_bf16(a3, bf0, acc[0][3], 0, 0, 0);  \
    acc[1][3] = __builtin_amdgcn_mfma_f32_16x16x32_bf16(a3, bf1, acc[1][3], 0, 0, 0);  \
  } while (0)

  LOADS(0, 0);
  LOADS(1, 1);
  LOADS(2, 2);
  LOADS(3, 3);

  int it = 0;
  for (; it < NIT - 4; it += 4) {
    DQMMA(0, it);     LOADS(0, it + 4);
    DQMMA(1, it + 1); LOADS(1, it + 5);
    DQMMA(2, it + 2); LOADS(2, it + 6);
    DQMMA(3, it + 3); LOADS(3, it + 7);
  }
  DQMMA(0, it);
  DQMMA(1, it + 1);
  DQMMA(2, it + 2);
  DQMMA(3, it + 3);

#undef LOADS
#undef DQMMA

  // C/D layout: col = lane&15, row = (lane>>4)*4 + r (verified m89)
  float* pout = partial + (size_t)s * BATCH * OUT_F;
  #pragma unroll
  for (int n = 0; n < 2; ++n) {
    int col = nb + n * 16 + l15;
    #pragma unroll
    for (int m = 0; m < 4; ++m) {
      int rowb = m * 16 + h * 4;
      #pragma unroll
      for (int r = 0; r < 4; ++r)
        pout[(size_t)(rowb + r) * OUT_F + col] = acc[n][m][r];
    }
  }
}

template <int KS>
__global__ void __launch_bounds__(256) reduce_kernel(const float* __restrict__ partial,
                                                     const float* __restrict__ bias,
                                                     float* __restrict__ out) {
  int i = blockIdx.x * 256 + threadIdx.x;
  float4 a = ((const float4*)partial)[i];
  #pragma unroll
  for (int s2 = 1; s2 < KS; ++s2) {
    float4 b = ((const float4*)partial)[i + s2 * (BATCH * OUT_F / 4)];
    a.x += b.x; a.y += b.y; a.z += b.z; a.w += b.w;
  }
  float4 bv = ((const float4*)bias)[i & (OUT_F / 4 - 1)];
  a.x += bv.x; a.y += bv.y; a.z += bv.z; a.w += bv.w;
  ((float4*)out)[i] = a;
}

extern "C" void kernel_launch(void* const* d_in, const int* in_sizes, int n_in,
                              void* d_out, int out_size, void* d_ws, size_t ws_size,
                              hipStream_t stream) {
  const float* x     = (const float*)d_in[0];
  const int*   wq    = (const int*)d_in[1];
  const float* wnorm = (const float*)d_in[2];
  const float* bias  = (const float*)d_in[3];
  float* out = (float*)d_out;

  const size_t xb_bytes = (size_t)BATCH * IN_F * 2;  // 1 MB
  ushort* xb      = (ushort*)d_ws;
  float*  partial = (float*)((char*)d_ws + xb_bytes);

  hipLaunchKernelGGL(xcvt_kernel, dim3(BATCH * IN_F / 4 / 256), dim3(256), 0, stream, x, xb);

  const size_t need8 = xb_bytes + (size_t)8 * BATCH * OUT_F * 4;  // ~17.8 MB
  if (ws_size >= need8) {
    hipLaunchKernelGGL((gemm3b_kernel<8>), dim3(OUT_F / 128, 8), dim3(256), 0, stream,
                       xb, wq, wnorm, partial);
    hipLaunchKernelGGL((reduce_kernel<8>), dim3(BATCH * OUT_F / 4 / 256), dim3(256), 0, stream,
                       partial, bias, out);
  } else {
    hipLaunchKernelGGL((gemm3b_kernel<4>), dim3(OUT_F / 128, 4), dim3(256), 0, stream,
                       xb, wq, wnorm, partial);
    hipLaunchKernelGGL((reduce_kernel<4>), dim3(BATCH * OUT_F / 4 / 256), dim3(256), 0, stream,
                       partial, bias, out);
  }
}